// Round 1
// baseline (177.749 us; speedup 1.0000x reference)
//
#include <hip/hip_runtime.h>
#include <hip/hip_bf16.h>
#include <stdint.h>

#define LQ 1024
#define BQ 2
#define AQ 14
#define KQ 30
#define EFQ 128
#define EDGE_IN 3152
#define KPAD 3200
#define NCHUNK 50
#define MTILE 128
#define ROWS (BQ*LQ*KQ)            /* 61440 */
#define EIDX_OFF (ROWS*EFQ)        /* 7864320 */

typedef __attribute__((ext_vector_type(8))) _Float16 half8;
typedef __attribute__((ext_vector_type(2))) _Float16 half2t;
typedef __attribute__((ext_vector_type(4))) float floatx4;
typedef unsigned long long ull;

static __device__ __forceinline__ uint32_t pkh(float a, float b) {
    auto h = __builtin_amdgcn_cvt_pkrtz(a, b);   // __fp16 ext_vector(2)
    return __builtin_bit_cast(uint32_t, h);
}
static __device__ __forceinline__ ull umin64(ull a, ull b) { return a < b ? a : b; }

// ---------------------------------------------------------------------------
// Kernel A v6 (unchanged): blocks 0..255 topk (8 rows/block, one wave per row,
// u64-packed keys); blocks 256..305: W fp32 -> f16 padded copy.
// ---------------------------------------------------------------------------
__global__ __launch_bounds__(512) void topk_kernel(
    const float* __restrict__ X, const float* __restrict__ mask,
    const float* __restrict__ W, float* __restrict__ out,
    int* __restrict__ idx_ws, _Float16* __restrict__ wpad)
{
    __shared__ float xs[LQ], ys[LQ], zs[LQ], ms[LQ];
    const int t = threadIdx.x;

    if (blockIdx.x >= 256) {                    // ---- merged wpad ----
        int base = (blockIdx.x - 256)*8192 + t; // 50 blocks x 8192 = 409600 exact
        #pragma unroll
        for (int r = 0; r < 16; ++r) {
            int idx = base + r*512;
            int n = idx / KPAD, f = idx - n*KPAD;
            float v = (f < EDGE_IN) ? W[(size_t)n*EDGE_IN + f] : 0.0f;
            wpad[idx] = (_Float16)v;
        }
        return;
    }

    const int w = t >> 6, lane = t & 63;
    const int row = blockIdx.x*8 + w;           // same b for whole block
    const int b = row >> 10, i = row & (LQ - 1);

    for (int j = t; j < LQ; j += 512) {
        size_t base = ((size_t)(b*LQ + j))*42 + 3;   // atom 1 (CA)
        xs[j] = X[base+0]; ys[j] = X[base+1]; zs[j] = X[base+2];
        ms[j] = mask[b*LQ + j];
    }
    __syncthreads();

    const float mif = ms[i];
    const double cx = (double)xs[i], cy = (double)ys[i], cz = (double)zs[i];

    double Dk[16]; float mf[16];
    bool allone = (mif == 1.0f);
    #pragma unroll
    for (int s = 0; s < 16; ++s) {
        int j = s*64 + lane;
        double dx = __dsub_rn(cx, (double)xs[j]);
        double dy = __dsub_rn(cy, (double)ys[j]);
        double dz = __dsub_rn(cz, (double)zs[j]);
        mf[s] = ms[j];
        Dk[s] = __dadd_rn(__dadd_rn(__dmul_rn(dx,dx), __dmul_rn(dy,dy)),
                          __dmul_rn(dz,dz));
        allone = allone && (mf[s] == 1.0f);
    }

    if (!__all(allone ? 1 : 0)) {
        // exact general path: D = mi*mj*sqrt(ssq+1e-6); key = D + 2(1-m2)*max(D)
        const double mi_d = (double)mif;
        double lm = 0.0;
        #pragma unroll
        for (int s = 0; s < 16; ++s) {
            double m2 = __dmul_rn(mi_d, (double)mf[s]);
            Dk[s] = __dmul_rn(m2, sqrt(__dadd_rn(Dk[s], 1e-6)));
            lm = fmax(lm, Dk[s]);
        }
        #pragma unroll
        for (int off = 32; off; off >>= 1) lm = fmax(lm, __shfl_xor(lm, off));
        #pragma unroll
        for (int s = 0; s < 16; ++s) {
            double m2 = __dmul_rn(mi_d, (double)mf[s]);
            Dk[s] = __dadd_rn(Dk[s],
                    __dmul_rn(__dmul_rn(2.0, __dsub_rn(1.0, m2)), lm));
        }
    }

    ull key[16];
    #pragma unroll
    for (int s = 0; s < 16; ++s)
        key[s] = (((ull)__double_as_longlong(Dk[s])) & ~1023ull)
               | (unsigned)(s*64 + lane);

    for (int k = 0; k < KQ; ++k) {
        ull a0 = umin64(key[0],  key[1]),  a1 = umin64(key[2],  key[3]);
        ull a2 = umin64(key[4],  key[5]),  a3 = umin64(key[6],  key[7]);
        ull a4 = umin64(key[8],  key[9]),  a5 = umin64(key[10], key[11]);
        ull a6 = umin64(key[12], key[13]), a7 = umin64(key[14], key[15]);
        ull b0 = umin64(a0, a1), b1 = umin64(a2, a3);
        ull b2 = umin64(a4, a5), b3 = umin64(a6, a7);
        ull bk = umin64(umin64(b0, b1), umin64(b2, b3));
        #pragma unroll
        for (int off = 32; off; off >>= 1)
            bk = umin64(bk, (ull)__shfl_xor(bk, off));
        int j = (int)(bk & 1023ull);
        if (lane == 0) {
            int rg = row*KQ + k;
            idx_ws[rg] = j;
            out[EIDX_OFF + rg] = (float)j;
        }
        bool mine = ((j & 63) == lane);
        int s_win = j >> 6;
        #pragma unroll
        for (int s = 0; s < 16; ++s)
            key[s] = (mine && s == s_win) ? ~0ull : key[s];
    }
}

// ---------------------------------------------------------------------------
// Kernel B v8: fused feature-gen + f16 MFMA GEMM + LayerNorm.
// 256-thread blocks, 4 waves, each wave owns 32 output rows (two 16-row MFMA
// groups sharing every B-fragment) -> B-side LDS read traffic halved vs v7.
// LDS 48.6 KB -> 3 blocks/CU (12 waves/CU).
// ---------------------------------------------------------------------------
struct FusedSmem {
    alignas(16) unsigned short atoms[256*56];  // f16 x,y,z,pad x 14 slots; 0..127 center, 128..255 neighbor
    alignas(16) unsigned short Bl[128*64];     // W chunk (f16 bits), XOR-swizzled
    alignas(16) float drow[MTILE];
    int residg[256];
    unsigned int maskb[256];
    float gsh[EFQ], bsh[EFQ];
};                                             // 48,640 B -> 3 blocks/CU

// Generate 8 contiguous features [f0, f0+8) for one row as 4 packed f16
// dwords. RBF: exp(-((d - r*4/3)*0.8)^2) = exp2(-(u - r*v)^2),
// u = d*0.96089846, v = 1.28119795. Dead pairs (mask or pad) poison u so all
// eight exp2 underflow to exact +0 (replaces 4 cndmasks with 1).
static __device__ __forceinline__ void gen8(
    const unsigned short* __restrict__ atomsA,
    const unsigned short* __restrict__ atomsB,
    unsigned maskA, unsigned maskB, float drowv,
    int f0, uint32_t* __restrict__ v)
{
    if (f0 >= 16) {
        int p = (f0 - 16) >> 4;
        int rbase = (f0 - 16) & 15;                 // == (q&1)*8
        int pc = p > 195 ? 195 : p;                 // clamp pad region to valid slot
        int a  = (pc * 74899) >> 20;                // pc / 14 for pc < 2048
        int bp = pc - a*14;
        bool dead = (p > 195) |
                    ((((maskA >> a) | (maskB >> bp)) & 1u) != 0u);
        half2t c0 = *reinterpret_cast<const half2t*>(atomsA + a*4);
        half2t c1 = *reinterpret_cast<const half2t*>(atomsA + a*4 + 2);
        half2t n0 = *reinterpret_cast<const half2t*>(atomsB + bp*4);
        half2t n1 = *reinterpret_cast<const half2t*>(atomsB + bp*4 + 2);
        half2t dxy = c0 - n0;                        // v_pk_add_f16
        half2t dzw = c1 - n1;
        float dx = (float)dxy[0], dy = (float)dxy[1], dz = (float)dzw[0];
        float u = __builtin_amdgcn_sqrtf(dx*dx + dy*dy + dz*dz + 1e-6f) * 0.96089846f;
        u = dead ? 1.0e4f : u;                       // exp2(-(~1e4)^2) -> +0 exactly
        #pragma unroll
        for (int k = 0; k < 4; ++k) {
            float t0 = __fmaf_rn(-(float)(rbase + 2*k),     1.28119795f, u);
            float t1 = __fmaf_rn(-(float)(rbase + 2*k + 1), 1.28119795f, u);
            v[k] = pkh(__builtin_amdgcn_exp2f(-(t0*t0)),
                       __builtin_amdgcn_exp2f(-(t1*t1)));
        }
    } else {
        const float fr[8] = {1.0f, 0.31622776601683794f, 0.1f,
            0.031622776601683794f, 0.01f, 0.0031622776601683794f,
            0.001f, 0.00031622776601683794f};
        float e[8];
        if (f0 == 0) {
            #pragma unroll
            for (int j = 0; j < 8; ++j) e[j] = __cosf(drowv * fr[j]);
        } else {
            #pragma unroll
            for (int j = 0; j < 8; ++j) e[j] = __sinf(drowv * fr[j]);
        }
        #pragma unroll
        for (int k = 0; k < 4; ++k) v[k] = pkh(e[2*k], e[2*k+1]);
    }
}

__global__ __launch_bounds__(256, 3) void fused_kernel(
    const float* __restrict__ X, const float* __restrict__ atom_mask,
    const _Float16* __restrict__ wpad, const float* __restrict__ gamma,
    const float* __restrict__ beta, const int* __restrict__ idx_ws,
    float* __restrict__ out)
{
    __shared__ FusedSmem sm;
    const int t = threadIdx.x;               // 0..255
    const int row0 = blockIdx.x * MTILE;
    const int b = row0 / (LQ*KQ);            // tiles never straddle b (30720 % 128 == 0)

    if (t < MTILE) {
        int rg = row0 + t;
        int rem = rg - b*(LQ*KQ);
        int i = rem / KQ;
        int j = idx_ws[rg];
        sm.residg[t]       = b*LQ + i;
        sm.residg[MTILE+t] = b*LQ + j;
        sm.drow[t] = (float)j - (float)i;
    }
    if (t < EFQ) { sm.gsh[t] = gamma[t]; sm.bsh[t] = beta[t]; }
    __syncthreads();

    // stage atoms: fp32 global -> packed f16 LDS (x,y,z,0 per slot)
    for (int u2 = t; u2 < 256*14; u2 += 256) {   // 14 exact iterations
        int s = u2 / 14; int a = u2 - s*14;
        const float* xp = X + (size_t)sm.residg[s]*42 + a*3;
        uint2 pk; pk.x = pkh(xp[0], xp[1]); pk.y = pkh(xp[2], 0.0f);
        *reinterpret_cast<uint2*>(&sm.atoms[s*56 + a*4]) = pk;
    }
    __syncthreads();

    {   // all 256 threads: Cb into slot 4 + mask bits, one residue each
        unsigned short* at = &sm.atoms[t*56];
        auto ld3 = [&](int slot, float& x, float& y, float& z) {
            half2t p0 = *reinterpret_cast<const half2t*>(at + slot*4);
            half2t p1 = *reinterpret_cast<const half2t*>(at + slot*4 + 2);
            x = (float)p0[0]; y = (float)p0[1]; z = (float)p1[0];
        };
        float Nx,Ny,Nz, Cax,Cay,Caz, Cx,Cy,Cz;
        ld3(0, Nx,Ny,Nz); ld3(1, Cax,Cay,Caz); ld3(2, Cx,Cy,Cz);
        float bx=Cax-Nx, by=Cay-Ny, bz=Caz-Nz;
        float ex=Cx-Cax, ey=Cy-Cay, ez=Cz-Caz;
        float ax = by*ez - bz*ey, ay = bz*ex - bx*ez, az = bx*ey - by*ex;
        float cbx = -0.58273431f*ax + 0.56802827f*bx - 0.54067466f*ex + Cax;
        float cby = -0.58273431f*ay + 0.56802827f*by - 0.54067466f*ey + Cay;
        float cbz = -0.58273431f*az + 0.56802827f*bz - 0.54067466f*ez + Caz;
        uint2 pk; pk.x = pkh(cbx, cby); pk.y = pkh(cbz, 0.0f);
        *reinterpret_cast<uint2*>(at + 4*4) = pk;    // slot 4 = Cb
        unsigned mb = 0;
        const float* amp = &atom_mask[(size_t)sm.residg[t]*AQ];
        #pragma unroll
        for (int a = 0; a < AQ; ++a) if (amp[a] > 0.5f) mb |= (1u << a);
        sm.maskb[t] = mb;
    }

    const int w = t >> 6, lane = t & 63, q = lane >> 4, l15 = lane & 15;
    const int m0 = w*32 + l15, m1 = m0 + 16;  // the wave's two 16-row groups

    // B-frag LDS offsets: boff(nt) = nt*1024 + cst (folds into ds_read imm)
    const int cst0 = l15*64 + ((q ^ (l15 & 7))*8);
    const int cst1 = l15*64 + (((4+q) ^ (l15 & 7))*8);

    // staging: 4 waves x 4 regions = 16 regions x (8 n-rows x 64 k)
    const _Float16* stBase[4];
    unsigned short* stDst[4];
    #pragma unroll
    for (int i2 = 0; i2 < 4; ++i2) {
        int region = w*4 + i2;                       // wave-uniform
        int n = region*8 + (lane >> 3);
        int kbsrc = (lane & 7) ^ (lane >> 3);
        stDst[i2]  = &sm.Bl[region*512];
        stBase[i2] = wpad + (size_t)n*KPAD + kbsrc*8;
    }

    floatx4 acc0[8], acc1[8];
    #pragma unroll
    for (int nt = 0; nt < 8; ++nt) {
        acc0[nt] = (floatx4){0.f,0.f,0.f,0.f};
        acc1[nt] = (floatx4){0.f,0.f,0.f,0.f};
    }

    __syncthreads();                          // atoms/maskb ready

    const unsigned short* atomsA0 = &sm.atoms[m0*56];
    const unsigned short* atomsB0 = &sm.atoms[(MTILE+m0)*56];
    const unsigned short* atomsA1 = &sm.atoms[m1*56];
    const unsigned short* atomsB1 = &sm.atoms[(MTILE+m1)*56];
    const unsigned maskA0 = sm.maskb[m0], maskB0 = sm.maskb[MTILE+m0];
    const unsigned maskA1 = sm.maskb[m1], maskB1 = sm.maskb[MTILE+m1];
    const float drow0 = sm.drow[m0], drow1 = sm.drow[m1];

    union H8 { uint32_t u[4]; half8 h; };
    for (int c = 0; c < NCHUNK; ++c) {
        if (c) __syncthreads();               // all reads of previous B chunk done
        #pragma unroll
        for (int i2 = 0; i2 < 4; ++i2) {      // async global->LDS, in flight during gen
            const _Float16* g = stBase[i2] + c*64;
            __builtin_amdgcn_global_load_lds(
                (const __attribute__((address_space(1))) uint32_t*)g,
                (__attribute__((address_space(3))) uint32_t*)stDst[i2],
                16, 0, 0);
        }
        H8 a00, a01, a10, a11;
        gen8(atomsA0, atomsB0, maskA0, maskB0, drow0, c*64 + q*8,      a00.u);
        gen8(atomsA0, atomsB0, maskA0, maskB0, drow0, c*64 + 32 + q*8, a01.u);
        gen8(atomsA1, atomsB1, maskA1, maskB1, drow1, c*64 + q*8,      a10.u);
        gen8(atomsA1, atomsB1, maskA1, maskB1, drow1, c*64 + 32 + q*8, a11.u);
        __syncthreads();                      // drains vmcnt: Bl ready
        #pragma unroll
        for (int nt = 0; nt < 8; ++nt) {
            half8 b0 = *reinterpret_cast<const half8*>(&sm.Bl[nt*1024 + cst0]);
            half8 b1 = *reinterpret_cast<const half8*>(&sm.Bl[nt*1024 + cst1]);
            acc0[nt] = __builtin_amdgcn_mfma_f32_16x16x32_f16(a00.h, b0, acc0[nt], 0, 0, 0);
            acc0[nt] = __builtin_amdgcn_mfma_f32_16x16x32_f16(a01.h, b1, acc0[nt], 0, 0, 0);
            acc1[nt] = __builtin_amdgcn_mfma_f32_16x16x32_f16(a10.h, b0, acc1[nt], 0, 0, 0);
            acc1[nt] = __builtin_amdgcn_mfma_f32_16x16x32_f16(a11.h, b1, acc1[nt], 0, 0, 0);
        }
    }

    // LayerNorm epilogue. C/D layout: col = lane&15, row = quad*4 + reg.
    auto lnrows = [&](const floatx4* acc, int gbase) {
        #pragma unroll
        for (int v = 0; v < 4; ++v) {
            float s = 0.f, s2 = 0.f;
            #pragma unroll
            for (int nt = 0; nt < 8; ++nt) { float x = acc[nt][v]; s += x; s2 += x*x; }
            #pragma unroll
            for (int off = 1; off < 16; off <<= 1) {
                s  += __shfl_xor(s,  off);
                s2 += __shfl_xor(s2, off);
            }
            float mean = s * (1.0f/128.0f);
            float var  = s2 * (1.0f/128.0f) - mean*mean;
            float rstd = 1.0f / sqrtf(var + 1e-5f);
            int row_l = w*32 + gbase + q*4 + v;
            size_t obase = (size_t)(row0 + row_l)*EFQ;
            #pragma unroll
            for (int nt = 0; nt < 8; ++nt) {
                int col = nt*16 + l15;
                out[obase + col] = (acc[nt][v] - mean)*rstd*sm.gsh[col] + sm.bsh[col];
            }
        }
    };
    lnrows(acc0, 0);
    lnrows(acc1, 16);
}

extern "C" void kernel_launch(void* const* d_in, const int* in_sizes, int n_in,
                              void* d_out, int out_size, void* d_ws, size_t ws_size,
                              hipStream_t stream)
{
    const float* X         = (const float*)d_in[0];
    const float* mask      = (const float*)d_in[1];
    // d_in[2] residue_idx, d_in[3] chain_labels: unused by the reference math
    const float* atom_mask = (const float*)d_in[4];
    const float* W         = (const float*)d_in[5];
    const float* gamma     = (const float*)d_in[6];
    const float* beta      = (const float*)d_in[7];
    float* out = (float*)d_out;

    int*       idx_ws = (int*)d_ws;                               // 61440*4 B
    _Float16*  wpad   = (_Float16*)((char*)d_ws + 262144);        // 128*3200*2 B

    hipLaunchKernelGGL(topk_kernel, dim3(306), dim3(512), 0, stream,
                       X, mask, W, out, idx_ws, wpad);
    hipLaunchKernelGGL(fused_kernel, dim3(ROWS/MTILE), dim3(256), 0, stream,
                       X, atom_mask, wpad, gamma, beta, idx_ws, out);
}